// Round 7
// baseline (42305.881 us; speedup 1.0000x reference)
//
#include <hip/hip_runtime.h>

#define NBLK 256
#define NTHR 512

// ---------------- math helpers ----------------
__device__ __forceinline__ float sigm(float x){ return 1.f/(1.f+__expf(-x)); }
__device__ __forceinline__ float tanh_(float x){ return 1.f - 2.f/(__expf(2.f*x)+1.f); }

__device__ __forceinline__ float wred_sum(float v){
  #pragma unroll
  for (int off=32; off; off>>=1) v += __shfl_xor(v, off, 64);
  return v;
}

// agent-coherent (sc1) store/load: write-through / L2-bypass read.
__device__ __forceinline__ void st_sys(float* p, float v){
  __hip_atomic_store(p, v, __ATOMIC_RELAXED, __HIP_MEMORY_SCOPE_AGENT);
}
__device__ __forceinline__ float ald(const float* p){
  return __hip_atomic_load(p, __ATOMIC_RELAXED, __HIP_MEMORY_SCOPE_AGENT);
}

// two-level arrive + TWO-LEVEL RELEASE grid barrier, epoch-based.
// uint32 slots spread 128B apart: grpArr[g]=g*32, rootArr=16*32,
// rootGen=17*32, grpGen[g]=(18+g)*32.  Max pollers per line = 16.
__device__ __forceinline__ void gsync(unsigned* bar, int w, unsigned& ep){
  ++ep;
  __builtin_amdgcn_s_waitcnt(0);          // drain this wave's sc1 stores
  __syncthreads();                         // all waves drained
  if (threadIdx.x == 0){
    const int g = w >> 4;
    const unsigned epoch = ep;
    bool rootfin = false;
    unsigned o = __hip_atomic_fetch_add(bar + g*32, 1u, __ATOMIC_ACQ_REL, __HIP_MEMORY_SCOPE_AGENT);
    if (o == 15u){                         // 16th arriver of this group
      __hip_atomic_store(bar + g*32, 0u, __ATOMIC_RELAXED, __HIP_MEMORY_SCOPE_AGENT);
      unsigned o2 = __hip_atomic_fetch_add(bar + 16*32, 1u, __ATOMIC_ACQ_REL, __HIP_MEMORY_SCOPE_AGENT);
      if (o2 == 15u){                      // last group in
        __hip_atomic_store(bar + 16*32, 0u, __ATOMIC_RELAXED, __HIP_MEMORY_SCOPE_AGENT);
        __hip_atomic_store(bar + 17*32, epoch, __ATOMIC_RELEASE, __HIP_MEMORY_SCOPE_AGENT);
        rootfin = true;
      }
    }
    if ((w & 15) == 0){                    // group leader: fan out
      if (!rootfin){
        while (__hip_atomic_load(bar + 17*32, __ATOMIC_RELAXED, __HIP_MEMORY_SCOPE_AGENT) < epoch)
          __builtin_amdgcn_s_sleep(1);
      }
      __hip_atomic_store(bar + (18+g)*32, epoch, __ATOMIC_RELEASE, __HIP_MEMORY_SCOPE_AGENT);
    } else {
      while (__hip_atomic_load(bar + (18+g)*32, __ATOMIC_RELAXED, __HIP_MEMORY_SCOPE_AGENT) < epoch)
        __builtin_amdgcn_s_sleep(1);
    }
  }
  __syncthreads();
}

// ---------------- LSTM layer (b-chunked LDS staging, 2-deep prefetch) ----
// WG owns 8 rows = 2 j x 4 gates; thread (r=tid>>6, s=tid&63) holds
// W[row][i*256 + s*4 + j] in registers. c lives in LDS (per WG, per layer).
// L0T: per-row x region [1024,1104) sourced from tgt (normal cached) --
// computed GENERICALLY from flat offset f (x lands in different i per row!).

template<int NI, bool L0T>
__device__ __forceinline__ void loadch(const float* __restrict__ in, int ch, int tid,
                                       const float* __restrict__ tgt, int t,
                                       float (&v)[NI][4]){
  const float* cb = in + ch*(NI<<11);          // 8 rows * NI*256 floats
  #pragma unroll
  for (int i=0;i<NI;++i){
    const int f = ((i<<9)+tid)<<2;
    if (L0T){
      const int bloc = f / 1280;               // row within chunk (0..7)
      const int k0   = f - bloc*1280;          // offset within row
      if (k0 < 1024){                          // ctx / h0 region: state ald
        #pragma unroll
        for (int j=0;j<4;++j) v[i][j] = ald(cb + f + j);
      } else if (k0 < 1104){                   // x region: from tgt, cached
        const int gb = (ch<<3) + bloc;
        #pragma unroll
        for (int j=0;j<4;++j) v[i][j] = tgt[((gb<<8) + t)*80 + (k0-1024) + j];
      } else {                                 // pad
        #pragma unroll
        for (int j=0;j<4;++j) v[i][j] = 0.f;
      }
    } else {
      #pragma unroll
      for (int j=0;j<4;++j) v[i][j] = ald(cb + f + j);
    }
  }
}

template<int NI>
__device__ __forceinline__ void stw(float* S, int tid, const float (&v)[NI][4]){
  #pragma unroll
  for (int i=0;i<NI;++i){
    float4 x = {v[i][0],v[i][1],v[i][2],v[i][3]};
    *(float4*)(S + (((i<<9)+tid)<<2)) = x;
  }
}

template<int NI>
__device__ __forceinline__ void cchunk(
    const float* S, int ch, int tid, int s, int r,
    const float (&wt)[NI][4], float breg,
    float* sc_c, float* sPart, float* sG4,
    int j0, float* __restrict__ dstA, int strA,
    float* __restrict__ dstB, int strB)
{
  float p[8];
  #pragma unroll
  for (int bb=0; bb<8; ++bb){
    const float* row = S + bb*(NI<<8) + (s<<2);
    float a0=0.f,a1=0.f,a2=0.f,a3=0.f;
    #pragma unroll
    for (int i=0;i<NI;++i){
      const float4 x = *(const float4*)(row + (i<<8));
      a0 = fmaf(wt[i][0], x.x, a0);
      a1 = fmaf(wt[i][1], x.y, a1);
      a2 = fmaf(wt[i][2], x.z, a2);
      a3 = fmaf(wt[i][3], x.w, a3);
    }
    p[bb] = (a0+a1)+(a2+a3);
  }
  #pragma unroll
  for (int bb=0; bb<8; ++bb)
    sPart[((((bb<<3)|r)<<6) | s)] = p[bb];
  __syncthreads();
  {
    const int seg = tid & 7, r2 = (tid>>3)&7, bb2 = tid>>6;
    const float* pp = sPart + (((bb2<<3)|r2)<<6) + (seg<<3);
    float v = ((pp[0]+pp[1])+(pp[2]+pp[3])) + ((pp[4]+pp[5])+(pp[6]+pp[7]));
    v += __shfl_xor(v,1,64);
    v += __shfl_xor(v,2,64);
    v += __shfl_xor(v,4,64);
    if (seg==0) sG4[(bb2<<3)|r2] = v + breg;
  }
  __syncthreads();
  if (tid < 16){
    const int bb = tid>>1, jl = tid&1;
    const int b = (ch<<3) + bb;
    const float gi = sigm (sG4[(bb<<3) + (jl<<2) + 0]);
    const float gf = sigm (sG4[(bb<<3) + (jl<<2) + 1]);
    const float gg = tanh_(sG4[(bb<<3) + (jl<<2) + 2]);
    const float go = sigm (sG4[(bb<<3) + (jl<<2) + 3]);
    const int j  = j0 + jl;
    const float cn = gf*sc_c[(ch<<4)+tid] + gi*gg;
    sc_c[(ch<<4)+tid] = cn;
    const float hn = go * tanh_(cn);
    st_sys(dstA + b*strA + j, hn);
    st_sys(dstB + b*strB + j, hn);
  }
}

template<int NI, bool L0T>
__device__ __forceinline__ void lstm_layer(
    int w, int tid, const float (&wt)[NI][4], float breg,
    const float* __restrict__ in, float* sc_c,
    float* __restrict__ dstA, int strA,
    float* __restrict__ dstB, int strB,
    float* S0, float* S1, float* sPart, float* sG4,
    const float* __restrict__ tgt, int t)
{
  const int s = tid & 63, r = tid >> 6, j0 = w << 1;
  float vA[NI][4], vB[NI][4];
  loadch<NI,L0T>(in, 0, tid, tgt, t, vA);
  loadch<NI,L0T>(in, 1, tid, tgt, t, vB);
  #pragma unroll 1
  for (int ch=0; ch<8; ch+=2){
    stw<NI>(S0, tid, vA);                            // waits vA
    if (ch+2 < 8) loadch<NI,L0T>(in, ch+2, tid, tgt, t, vA);   // 2-deep prefetch
    __syncthreads();
    cchunk<NI>(S0, ch,   tid,s,r, wt,breg, sc_c,sPart,sG4, j0, dstA,strA, dstB,strB);
    stw<NI>(S1, tid, vB);                            // vB issued ~2 chunks ago
    if (ch+3 < 8) loadch<NI,L0T>(in, ch+3, tid, tgt, t, vB);
    __syncthreads();
    cchunk<NI>(S1, ch+1, tid,s,r, wt,breg, sc_c,sPart,sG4, j0, dstA,strA, dstB,strB);
  }
}

// ws float offsets (after 8KB barrier area)
#define IN0_OFF   0            // [2][64][1280]  [ctx 0:512][h0 512:1024][x unused]
#define IN1_OFF   163840       // [2][64][1024]  [h0_new | h1_old]
#define IN2_OFF   294912       // [2][64][1024]  [h1_new | h2_old]
#define H2_OFF    425984       // [64][512]
#define QP_OFF    557056       // [4][64][512]
#define PC_OFF    688128       // [4][64][512]
#define MS_OFF    819200       // [4][64][2]
#define ZERO_CNT  458752       // IN0,IN1,IN2,H2

__global__ __launch_bounds__(NTHR, 2)
void sd_kernel(const float* __restrict__ tgt,  const float* __restrict__ enc,
               const int*   __restrict__ lens,
               const float* __restrict__ Wih0, const float* __restrict__ Whh0, const float* __restrict__ b0v,
               const float* __restrict__ Wih1, const float* __restrict__ Whh1, const float* __restrict__ b1v,
               const float* __restrict__ Wih2, const float* __restrict__ Whh2, const float* __restrict__ b2v,
               const float* __restrict__ Wq,   const float* __restrict__ Wfc,  const float* __restrict__ bfc,
               float* __restrict__ out, void* __restrict__ wsv)
{
  unsigned* bar = (unsigned*)wsv;
  float* base = (float*)((char*)wsv + 8192);
  float* IN0 = base + IN0_OFF;
  float* IN1 = base + IN1_OFF;
  float* IN2 = base + IN2_OFF;
  float* H2  = base + H2_OFF;
  float* QP  = base + QP_OFF;
  float* PC  = base + PC_OFF;
  float* MS  = base + MS_OFF;

  const int w = blockIdx.x, tid = threadIdx.x;
  const int s = tid & 63, r = tid >> 6;
  unsigned ep = 0;

  __shared__ __attribute__((aligned(16))) float sStage0[10240];
  __shared__ __attribute__((aligned(16))) float sStage1[10240];
  __shared__ __attribute__((aligned(16))) float sBig[4096];
  __shared__ __attribute__((aligned(16))) float sG4[64];
  __shared__ __attribute__((aligned(16))) float sVec[512];
  __shared__ __attribute__((aligned(16))) float sSmall[16];
  __shared__ __attribute__((aligned(16))) float sc_c[384];

  // ---- prologue: weights -> registers (normal cached; read-only) ----
  const int wrow  = ((r&3)<<9) + (w<<1) + (r>>2);
  const int r2p   = (tid>>3)&7;
  const int wrowb = ((r2p&3)<<9) + (w<<1) + (r2p>>2);

  float w0r[5][4], w1r[4][4], w2r[4][4];
  #pragma unroll
  for (int i=0;i<5;++i){
    #pragma unroll
    for (int j=0;j<4;++j){
      const int k = (i<<8) + (s<<2) + j;
      float v;
      if (k < 512)       v = Wih0[wrow*592 + 80 + k];        // ctx block
      else if (k < 1024) v = Whh0[(wrow<<9) + (k-512)];      // h0 block
      else if (k < 1104) v = Wih0[wrow*592 + (k-1024)];      // x block
      else               v = 0.f;                            // pad
      w0r[i][j] = v;
    }
  }
  #pragma unroll
  for (int i=0;i<4;++i){
    #pragma unroll
    for (int j=0;j<4;++j){
      const int k = (i<<8) + (s<<2) + j;
      w1r[i][j] = (k<512) ? Wih1[(wrow<<9)+k] : Whh1[(wrow<<9)+k-512];
      w2r[i][j] = (k<512) ? Wih2[(wrow<<9)+k] : Whh2[(wrow<<9)+k-512];
    }
  }
  const float br0 = b0v[wrowb], br1 = b1v[wrowb], br2 = b2v[wrowb];

  if (tid < 384) sc_c[tid] = 0.f;
  for (int i = w*NTHR + tid; i < ZERO_CNT; i += NBLK*NTHR) st_sys(base + i, 0.f);
  gsync(bar, w, ep);

  for (int t=0; t<255; ++t){
    const int p = t & 1, np = p ^ 1;
    float* IN0p = IN0 + p*81920;  float* IN0n = IN0 + np*81920;
    float* IN1p = IN1 + p*65536;  float* IN1n = IN1 + np*65536;
    float* IN2p = IN2 + p*65536;  float* IN2n = IN2 + np*65536;

    lstm_layer<5,true >(w,tid, w0r, br0, IN0p, sc_c,     IN0n+512, 1280, IN1p, 1024, sStage0,sStage1, sBig, sG4, tgt, t);
    gsync(bar,w,ep);
    lstm_layer<4,false>(w,tid, w1r, br1, IN1p, sc_c+128, IN1n+512, 1024, IN2p, 1024, sStage0,sStage1, sBig, sG4, tgt, t);
    gsync(bar,w,ep);
    lstm_layer<4,false>(w,tid, w2r, br2, IN2p, sc_c+256, IN2n+512, 1024, H2,   512,  sStage0,sStage1, sBig, sG4, tgt, t);
    gsync(bar,w,ep);

    // ---- q partials: WG (b = w&63, kq = w>>6) over k-quarter ----
    {
      const int b = w & 63, kq = w >> 6;
      if (tid < 128) sVec[tid] = ald(&H2[(b<<9) + (kq<<7) + tid]);
      __syncthreads();
      const float* wqp = Wq + ((size_t)(kq<<7)<<9) + tid;     // normal cached (L2-hot)
      float acc = 0.f;
      #pragma unroll 4
      for (int k=0;k<128;++k) acc = fmaf(sVec[k], wqp[(size_t)k<<9], acc);
      st_sys(&QP[(((kq<<6)+b)<<9) + tid], acc);
    }
    gsync(bar,w,ep);

    // ---- attention A: WG (b, sq): online-softmax over 128 enc rows ----
    {
      const int b = w & 63, sq = w >> 6;
      const int len  = lens[b];
      const int lane = tid & 63, wv = tid >> 6;
      sVec[tid] = ald(&QP[(b<<9)+tid]) + ald(&QP[((64+b)<<9)+tid])
                + ald(&QP[((128+b)<<9)+tid]) + ald(&QP[((192+b)<<9)+tid]);
      __syncthreads();
      const float4 qA = *(const float4*)(sVec + (lane<<3));
      const float4 qB = *(const float4*)(sVec + (lane<<3) + 4);
      float mr = -3.0e38f, lr = 0.f;
      float c0=0,c1=0,c2=0,c3=0,c4=0,c5=0,c6=0,c7=0;
      const float scale = 0.04419417382415922f;   // 1/sqrt(512)
      #pragma unroll 1
      for (int rr=0; rr<16; ++rr){
        const int srow = (sq<<7) + (wv<<4) + rr;     // wave-uniform
        if (srow >= len) break;                       // rows monotonic
        const float* ep2 = enc + (((size_t)(b<<9)+srow)<<9) + (lane<<3);  // cached
        const float4 e0 = *(const float4*)(ep2);
        const float4 e1 = *(const float4*)(ep2+4);
        float d0 = qA.x*e0.x, d1 = qA.y*e0.y, d2 = qA.z*e0.z, d3 = qA.w*e0.w;
        d0 = fmaf(qB.x, e1.x, d0); d1 = fmaf(qB.y, e1.y, d1);
        d2 = fmaf(qB.z, e1.z, d2); d3 = fmaf(qB.w, e1.w, d3);
        float d = wred_sum((d0+d1)+(d2+d3));
        const float sc = d*scale;
        const float mn = fmaxf(mr, sc);
        const float sf = __expf(mr - mn);
        const float pe = __expf(sc - mn);
        lr = fmaf(lr, sf, pe);
        c0 = fmaf(c0, sf, pe*e0.x); c1 = fmaf(c1, sf, pe*e0.y);
        c2 = fmaf(c2, sf, pe*e0.z); c3 = fmaf(c3, sf, pe*e0.w);
        c4 = fmaf(c4, sf, pe*e1.x); c5 = fmaf(c5, sf, pe*e1.y);
        c6 = fmaf(c6, sf, pe*e1.z); c7 = fmaf(c7, sf, pe*e1.w);
        mr = mn;
      }
      if (lane==0){ sSmall[wv] = mr; sSmall[8+wv] = lr; }
      {
        float4 v0 = {c0,c1,c2,c3}, v1 = {c4,c5,c6,c7};
        *(float4*)(sBig + (wv<<9) + (lane<<3))     = v0;
        *(float4*)(sBig + (wv<<9) + (lane<<3) + 4) = v1;
      }
      __syncthreads();
      float M = sSmall[0];
      #pragma unroll
      for (int i=1;i<8;++i) M = fmaxf(M, sSmall[i]);
      float L = 0.f, acc = 0.f;
      #pragma unroll
      for (int i=0;i<8;++i){
        const float A = __expf(sSmall[i]-M);
        L   = fmaf(A, sSmall[8+i], L);
        acc = fmaf(A, sBig[(i<<9)+tid], acc);
      }
      st_sys(&PC[(((sq<<6)+b)<<9)+tid], acc);
      if (tid==0){
        st_sys(&MS[(((sq<<6)+b)<<1)],   M);
        st_sys(&MS[(((sq<<6)+b)<<1)+1], L);
      }
    }
    gsync(bar,w,ep);

    // ---- attention B: combine + FC + out (WGs 0..63 only) ----
    if (w < 64){
      const int b = w;
      const float m0 = ald(&MS[(b)<<1]),      S0 = ald(&MS[((b)<<1)+1]);
      const float m1 = ald(&MS[(64+b)<<1]),   S1 = ald(&MS[((64+b)<<1)+1]);
      const float m2 = ald(&MS[(128+b)<<1]),  S2 = ald(&MS[((128+b)<<1)+1]);
      const float m3 = ald(&MS[(192+b)<<1]),  S3 = ald(&MS[((192+b)<<1)+1]);
      const float M  = fmaxf(fmaxf(m0,m1), fmaxf(m2,m3));
      const float a0=__expf(m0-M), a1=__expf(m1-M), a2=__expf(m2-M), a3=__expf(m3-M);
      const float inv = 1.f/(a0*S0 + a1*S1 + a2*S2 + a3*S3);
      const float c = (a0*ald(&PC[(b<<9)+tid])       + a1*ald(&PC[((64+b)<<9)+tid])
                     + a2*ald(&PC[((128+b)<<9)+tid]) + a3*ald(&PC[((192+b)<<9)+tid])) * inv;
      st_sys(&IN0n[b*1280 + tid], c);      // ctx slot for L0(t+1)
      sVec[tid] = c;
      __syncthreads();
      if (tid < 80){
        float acc = 0.f;
        #pragma unroll 4
        for (int e2=0;e2<512;++e2) acc = fmaf(sVec[e2], Wfc[e2*80+tid], acc);  // cached
        out[((size_t)b*255 + t)*80 + tid] = acc + bfc[tid];
      }
    }
    gsync(bar,w,ep);
  }
}

extern "C" void kernel_launch(void* const* d_in, const int* in_sizes, int n_in,
                              void* d_out, int out_size, void* d_ws, size_t ws_size,
                              hipStream_t stream) {
  const float* tgt  = (const float*)d_in[0];
  const float* enc  = (const float*)d_in[1];
  const int*   lens = (const int*)  d_in[2];
  const float* Wih0 = (const float*)d_in[3];
  const float* Whh0 = (const float*)d_in[4];
  const float* b0   = (const float*)d_in[5];
  const float* Wih1 = (const float*)d_in[6];
  const float* Whh1 = (const float*)d_in[7];
  const float* b1   = (const float*)d_in[8];
  const float* Wih2 = (const float*)d_in[9];
  const float* Whh2 = (const float*)d_in[10];
  const float* b2   = (const float*)d_in[11];
  const float* Wq   = (const float*)d_in[12];
  const float* Wfc  = (const float*)d_in[13];
  const float* bfc  = (const float*)d_in[14];

  hipMemsetAsync(d_ws, 0, 8192, stream);   // barrier counters (34 spread slots)
  sd_kernel<<<NBLK, NTHR, 0, stream>>>(tgt, enc, lens,
                                       Wih0, Whh0, b0,
                                       Wih1, Whh1, b1,
                                       Wih2, Whh2, b2,
                                       Wq, Wfc, bfc,
                                       (float*)d_out, d_ws);
}

// Round 9
// 38123.834 us; speedup vs baseline: 1.1097x; 1.1097x over previous
//
#include <hip/hip_runtime.h>

#define NBLK 256
#define NTHR 512

typedef float f32x4 __attribute__((ext_vector_type(4)));

// ---------------- math helpers ----------------
__device__ __forceinline__ float sigm(float x){ return 1.f/(1.f+__expf(-x)); }
__device__ __forceinline__ float tanh_(float x){ return 1.f - 2.f/(__expf(2.f*x)+1.f); }

__device__ __forceinline__ float wred_sum(float v){
  #pragma unroll
  for (int off=32; off; off>>=1) v += __shfl_xor(v, off, 64);
  return v;
}

// agent-coherent (sc1) store/load: write-through / L2-bypass read.
__device__ __forceinline__ void st_sys(float* p, float v){
  __hip_atomic_store(p, v, __ATOMIC_RELAXED, __HIP_MEMORY_SCOPE_AGENT);
}
__device__ __forceinline__ float ald(const float* p){
  return __hip_atomic_load(p, __ATOMIC_RELAXED, __HIP_MEMORY_SCOPE_AGENT);
}
// 16B coherent load: issue (no wait) -- 4x fewer fabric transactions than 4 dwords
__device__ __forceinline__ void ald4_issue(const float* p, f32x4& v){
  asm volatile("global_load_dwordx4 %0, %1, off sc0 sc1" : "=v"(v) : "v"(p));
}
__device__ __forceinline__ void vm_wait0(){
  asm volatile("s_waitcnt vmcnt(0)" ::: "memory");
  __builtin_amdgcn_sched_barrier(0);
}

// two-level arrive + two-level release grid barrier, epoch-based (proven r7).
__device__ __forceinline__ void gsync(unsigned* bar, int w, unsigned& ep){
  ++ep;
  __builtin_amdgcn_s_waitcnt(0);          // drain this wave's sc1 stores
  __syncthreads();                         // all waves drained
  if (threadIdx.x == 0){
    const int g = w >> 4;
    const unsigned epoch = ep;
    bool rootfin = false;
    unsigned o = __hip_atomic_fetch_add(bar + g*32, 1u, __ATOMIC_ACQ_REL, __HIP_MEMORY_SCOPE_AGENT);
    if (o == 15u){
      __hip_atomic_store(bar + g*32, 0u, __ATOMIC_RELAXED, __HIP_MEMORY_SCOPE_AGENT);
      unsigned o2 = __hip_atomic_fetch_add(bar + 16*32, 1u, __ATOMIC_ACQ_REL, __HIP_MEMORY_SCOPE_AGENT);
      if (o2 == 15u){
        __hip_atomic_store(bar + 16*32, 0u, __ATOMIC_RELAXED, __HIP_MEMORY_SCOPE_AGENT);
        __hip_atomic_store(bar + 17*32, epoch, __ATOMIC_RELEASE, __HIP_MEMORY_SCOPE_AGENT);
        rootfin = true;
      }
    }
    if ((w & 15) == 0){
      if (!rootfin){
        while (__hip_atomic_load(bar + 17*32, __ATOMIC_RELAXED, __HIP_MEMORY_SCOPE_AGENT) < epoch)
          __builtin_amdgcn_s_sleep(1);
      }
      __hip_atomic_store(bar + (18+g)*32, epoch, __ATOMIC_RELEASE, __HIP_MEMORY_SCOPE_AGENT);
    } else {
      while (__hip_atomic_load(bar + (18+g)*32, __ATOMIC_RELAXED, __HIP_MEMORY_SCOPE_AGENT) < epoch)
        __builtin_amdgcn_s_sleep(1);
    }
  }
  __syncthreads();
}

// ---------------- LSTM layer (r7 all-b tiling, vectorized sc1 staging) ----
// WG w owns 8 gate-rows = 2 j x 4 gates; thread (r=tid>>6, s=tid&63) holds
// W[row][i*256 + s*4 + j] in registers. Chunk = 8 batch rows staged to LDS.

template<int NI, bool L0T>
__device__ __forceinline__ void loadch_sync(const float* __restrict__ in, int ch, int tid,
                                            const float* __restrict__ tgt, int t,
                                            f32x4 (&v)[NI]){
  const float* cb = in + ch*(NI<<11);          // 8 rows * NI*256 floats
  #pragma unroll
  for (int i=0;i<NI;++i){
    const int f = ((i<<9)+tid)<<2;
    if (L0T){
      const int bloc = f / 1280;               // row within chunk (0..7)
      const int k0   = f - bloc*1280;          // offset within row
      if (k0 < 1024){                          // ctx / h0: coherent 16B load
        ald4_issue(cb + f, v[i]);
      } else if (k0 < 1104){                   // x: from tgt, normal cached
        const int gb = (ch<<3) + bloc;
        v[i] = *(const f32x4*)(tgt + ((gb<<8) + t)*80 + (k0-1024));
      } else {                                 // pad
        v[i] = (f32x4){0.f,0.f,0.f,0.f};
      }
    } else {
      ald4_issue(cb + f, v[i]);
    }
  }
  vm_wait0();                                  // all NI loads (and tgt) resident
}

template<int NI>
__device__ __forceinline__ void stw(float* S, int tid, const f32x4 (&v)[NI]){
  #pragma unroll
  for (int i=0;i<NI;++i)
    *(f32x4*)(S + (((i<<9)+tid)<<2)) = v[i];
}

template<int NI>
__device__ __forceinline__ void cchunk(
    const float* S, int ch, int tid, int s, int r,
    const float (&wt)[NI][4], float breg,
    float* sc_c, float* sPart, float* sG4,
    int j0, float* __restrict__ dstA, int strA,
    float* __restrict__ dstB, int strB)
{
  float p[8];
  #pragma unroll
  for (int bb=0; bb<8; ++bb){
    const float* row = S + bb*(NI<<8) + (s<<2);
    float a0=0.f,a1=0.f,a2=0.f,a3=0.f;
    #pragma unroll
    for (int i=0;i<NI;++i){
      const float4 x = *(const float4*)(row + (i<<8));
      a0 = fmaf(wt[i][0], x.x, a0);
      a1 = fmaf(wt[i][1], x.y, a1);
      a2 = fmaf(wt[i][2], x.z, a2);
      a3 = fmaf(wt[i][3], x.w, a3);
    }
    p[bb] = (a0+a1)+(a2+a3);
  }
  #pragma unroll
  for (int bb=0; bb<8; ++bb)
    sPart[((((bb<<3)|r)<<6) | s)] = p[bb];
  __syncthreads();
  {
    const int seg = tid & 7, r2 = (tid>>3)&7, bb2 = tid>>6;
    const float* pp = sPart + (((bb2<<3)|r2)<<6) + (seg<<3);
    float v = ((pp[0]+pp[1])+(pp[2]+pp[3])) + ((pp[4]+pp[5])+(pp[6]+pp[7]));
    v += __shfl_xor(v,1,64);
    v += __shfl_xor(v,2,64);
    v += __shfl_xor(v,4,64);
    if (seg==0) sG4[(bb2<<3)|r2] = v + breg;
  }
  __syncthreads();
  if (tid < 16){
    const int bb = tid>>1, jl = tid&1;
    const int b = (ch<<3) + bb;
    const float gi = sigm (sG4[(bb<<3) + (jl<<2) + 0]);
    const float gf = sigm (sG4[(bb<<3) + (jl<<2) + 1]);
    const float gg = tanh_(sG4[(bb<<3) + (jl<<2) + 2]);
    const float go = sigm (sG4[(bb<<3) + (jl<<2) + 3]);
    const int j  = j0 + jl;
    const float cn = gf*sc_c[(ch<<4)+tid] + gi*gg;
    sc_c[(ch<<4)+tid] = cn;
    const float hn = go * tanh_(cn);
    st_sys(dstA + b*strA + j, hn);
    st_sys(dstB + b*strB + j, hn);
  }
}

template<int NI, bool L0T>
__device__ __forceinline__ void lstm_layer(
    int w, int tid, const float (&wt)[NI][4], float breg,
    const float* __restrict__ in, float* sc_c,
    float* __restrict__ dstA, int strA,
    float* __restrict__ dstB, int strB,
    float* S, float* sPart, float* sG4,
    const float* __restrict__ tgt, int t)
{
  const int s = tid & 63, r = tid >> 6, j0 = w << 1;
  f32x4 v[NI];
  #pragma unroll 1
  for (int ch=0; ch<8; ++ch){
    loadch_sync<NI,L0T>(in, ch, tid, tgt, t, v);
    stw<NI>(S, tid, v);
    __syncthreads();                          // S visible to all
    cchunk<NI>(S, ch, tid,s,r, wt,breg, sc_c,sPart,sG4, j0, dstA,strA, dstB,strB);
  }
}

// ws float offsets (after 8KB barrier area)
#define IN0_OFF   0            // [2][64][1280]  [ctx 0:512][h0 512:1024][x unused]
#define IN1_OFF   163840       // [2][64][1024]  [h0_new | h1_old]
#define IN2_OFF   294912       // [2][64][1024]  [h1_new | h2_old]
#define H2_OFF    425984       // [64][512]
#define QP_OFF    557056       // [4][64][512]
#define PC_OFF    688128       // [4][64][512]
#define MS_OFF    819200       // [4][64][2]
#define ZERO_CNT  458752       // IN0,IN1,IN2,H2

__global__ __launch_bounds__(NTHR, 2)
void sd_kernel(const float* __restrict__ tgt,  const float* __restrict__ enc,
               const int*   __restrict__ lens,
               const float* __restrict__ Wih0, const float* __restrict__ Whh0, const float* __restrict__ b0v,
               const float* __restrict__ Wih1, const float* __restrict__ Whh1, const float* __restrict__ b1v,
               const float* __restrict__ Wih2, const float* __restrict__ Whh2, const float* __restrict__ b2v,
               const float* __restrict__ Wq,   const float* __restrict__ Wfc,  const float* __restrict__ bfc,
               float* __restrict__ out, void* __restrict__ wsv)
{
  unsigned* bar = (unsigned*)wsv;
  float* base = (float*)((char*)wsv + 8192);
  float* IN0 = base + IN0_OFF;
  float* IN1 = base + IN1_OFF;
  float* IN2 = base + IN2_OFF;
  float* H2  = base + H2_OFF;
  float* QP  = base + QP_OFF;
  float* PC  = base + PC_OFF;
  float* MS  = base + MS_OFF;

  const int w = blockIdx.x, tid = threadIdx.x;
  const int s = tid & 63, r = tid >> 6;
  unsigned ep = 0;

  __shared__ __attribute__((aligned(16))) float sStage[10240];  // single stage buf (2 WG/CU)
  __shared__ __attribute__((aligned(16))) float sBig[4096];
  __shared__ __attribute__((aligned(16))) float sG4[64];
  __shared__ __attribute__((aligned(16))) float sVec[512];
  __shared__ __attribute__((aligned(16))) float sSmall[16];
  __shared__ __attribute__((aligned(16))) float sc_c[384];      // 128 cells PER LAYER

  // ---- prologue: weights -> registers (normal cached; read-only) ----
  const int wrow  = ((r&3)<<9) + (w<<1) + (r>>2);
  const int r2p   = (tid>>3)&7;
  const int wrowb = ((r2p&3)<<9) + (w<<1) + (r2p>>2);

  float w0r[5][4], w1r[4][4], w2r[4][4];
  #pragma unroll
  for (int i=0;i<5;++i){
    #pragma unroll
    for (int j=0;j<4;++j){
      const int k = (i<<8) + (s<<2) + j;
      float v;
      if (k < 512)       v = Wih0[wrow*592 + 80 + k];        // ctx block
      else if (k < 1024) v = Whh0[(wrow<<9) + (k-512)];      // h0 block
      else if (k < 1104) v = Wih0[wrow*592 + (k-1024)];      // x block
      else               v = 0.f;                            // pad
      w0r[i][j] = v;
    }
  }
  #pragma unroll
  for (int i=0;i<4;++i){
    #pragma unroll
    for (int j=0;j<4;++j){
      const int k = (i<<8) + (s<<2) + j;
      w1r[i][j] = (k<512) ? Wih1[(wrow<<9)+k] : Whh1[(wrow<<9)+k-512];
      w2r[i][j] = (k<512) ? Wih2[(wrow<<9)+k] : Whh2[(wrow<<9)+k-512];
    }
  }
  const float br0 = b0v[wrowb], br1 = b1v[wrowb], br2 = b2v[wrowb];

  if (tid < 384) sc_c[tid] = 0.f;
  for (int i = w*NTHR + tid; i < ZERO_CNT; i += NBLK*NTHR) st_sys(base + i, 0.f);
  gsync(bar, w, ep);

  for (int t=0; t<255; ++t){
    const int p = t & 1, np = p ^ 1;
    float* IN0p = IN0 + p*81920;  float* IN0n = IN0 + np*81920;
    float* IN1p = IN1 + p*65536;  float* IN1n = IN1 + np*65536;
    float* IN2p = IN2 + p*65536;  float* IN2n = IN2 + np*65536;

    lstm_layer<5,true >(w,tid, w0r, br0, IN0p, sc_c,     IN0n+512, 1280, IN1p, 1024, sStage, sBig, sG4, tgt, t);
    gsync(bar,w,ep);
    lstm_layer<4,false>(w,tid, w1r, br1, IN1p, sc_c+128, IN1n+512, 1024, IN2p, 1024, sStage, sBig, sG4, tgt, t);
    gsync(bar,w,ep);
    lstm_layer<4,false>(w,tid, w2r, br2, IN2p, sc_c+256, IN2n+512, 1024, H2,   512,  sStage, sBig, sG4, tgt, t);
    gsync(bar,w,ep);

    // ---- q partials: WG (b = w&63, kq = w>>6) over k-quarter ----
    {
      const int b = w & 63, kq = w >> 6;
      if (tid < 128) sVec[tid] = ald(&H2[(b<<9) + (kq<<7) + tid]);
      __syncthreads();
      const float* wqp = Wq + ((size_t)(kq<<7)<<9) + tid;     // normal cached (L2-hot)
      float acc = 0.f;
      #pragma unroll 4
      for (int k=0;k<128;++k) acc = fmaf(sVec[k], wqp[(size_t)k<<9], acc);
      st_sys(&QP[(((kq<<6)+b)<<9) + tid], acc);
    }
    gsync(bar,w,ep);

    // ---- attention A: WG (b, sq): online-softmax over 128 enc rows ----
    {
      const int b = w & 63, sq = w >> 6;
      const int len  = lens[b];
      const int lane = tid & 63, wv = tid >> 6;
      sVec[tid] = ald(&QP[(b<<9)+tid]) + ald(&QP[((64+b)<<9)+tid])
                + ald(&QP[((128+b)<<9)+tid]) + ald(&QP[((192+b)<<9)+tid]);
      __syncthreads();
      const float4 qA = *(const float4*)(sVec + (lane<<3));
      const float4 qB = *(const float4*)(sVec + (lane<<3) + 4);
      float mr = -3.0e38f, lr = 0.f;
      float c0=0,c1=0,c2=0,c3=0,c4=0,c5=0,c6=0,c7=0;
      const float scale = 0.04419417382415922f;   // 1/sqrt(512)
      #pragma unroll 1
      for (int rr=0; rr<16; ++rr){
        const int srow = (sq<<7) + (wv<<4) + rr;     // wave-uniform
        if (srow >= len) break;                       // rows monotonic
        const float* ep2 = enc + (((size_t)(b<<9)+srow)<<9) + (lane<<3);  // cached
        const float4 e0 = *(const float4*)(ep2);
        const float4 e1 = *(const float4*)(ep2+4);
        float d0 = qA.x*e0.x, d1 = qA.y*e0.y, d2 = qA.z*e0.z, d3 = qA.w*e0.w;
        d0 = fmaf(qB.x, e1.x, d0); d1 = fmaf(qB.y, e1.y, d1);
        d2 = fmaf(qB.z, e1.z, d2); d3 = fmaf(qB.w, e1.w, d3);
        float d = wred_sum((d0+d1)+(d2+d3));
        const float sc = d*scale;
        const float mn = fmaxf(mr, sc);
        const float sf = __expf(mr - mn);
        const float pe = __expf(sc - mn);
        lr = fmaf(lr, sf, pe);
        c0 = fmaf(c0, sf, pe*e0.x); c1 = fmaf(c1, sf, pe*e0.y);
        c2 = fmaf(c2, sf, pe*e0.z); c3 = fmaf(c3, sf, pe*e0.w);
        c4 = fmaf(c4, sf, pe*e1.x); c5 = fmaf(c5, sf, pe*e1.y);
        c6 = fmaf(c6, sf, pe*e1.z); c7 = fmaf(c7, sf, pe*e1.w);
        mr = mn;
      }
      if (lane==0){ sSmall[wv] = mr; sSmall[8+wv] = lr; }
      {
        float4 v0 = {c0,c1,c2,c3}, v1 = {c4,c5,c6,c7};
        *(float4*)(sBig + (wv<<9) + (lane<<3))     = v0;
        *(float4*)(sBig + (wv<<9) + (lane<<3) + 4) = v1;
      }
      __syncthreads();
      float M = sSmall[0];
      #pragma unroll
      for (int i=1;i<8;++i) M = fmaxf(M, sSmall[i]);
      float L = 0.f, acc = 0.f;
      #pragma unroll
      for (int i=0;i<8;++i){
        const float A = __expf(sSmall[i]-M);
        L   = fmaf(A, sSmall[8+i], L);
        acc = fmaf(A, sBig[(i<<9)+tid], acc);
      }
      st_sys(&PC[(((sq<<6)+b)<<9)+tid], acc);
      if (tid==0){
        st_sys(&MS[(((sq<<6)+b)<<1)],   M);
        st_sys(&MS[(((sq<<6)+b)<<1)+1], L);
      }
    }
    gsync(bar,w,ep);

    // ---- attention B: combine + FC + out (WGs 0..63 only) ----
    if (w < 64){
      const int b = w;
      const float m0 = ald(&MS[(b)<<1]),      S0 = ald(&MS[((b)<<1)+1]);
      const float m1 = ald(&MS[(64+b)<<1]),   S1 = ald(&MS[((64+b)<<1)+1]);
      const float m2 = ald(&MS[(128+b)<<1]),  S2 = ald(&MS[((128+b)<<1)+1]);
      const float m3 = ald(&MS[(192+b)<<1]),  S3 = ald(&MS[((192+b)<<1)+1]);
      const float M  = fmaxf(fmaxf(m0,m1), fmaxf(m2,m3));
      const float a0=__expf(m0-M), a1=__expf(m1-M), a2=__expf(m2-M), a3=__expf(m3-M);
      const float inv = 1.f/(a0*S0 + a1*S1 + a2*S2 + a3*S3);
      const float c = (a0*ald(&PC[(b<<9)+tid])       + a1*ald(&PC[((64+b)<<9)+tid])
                     + a2*ald(&PC[((128+b)<<9)+tid]) + a3*ald(&PC[((192+b)<<9)+tid])) * inv;
      st_sys(&IN0n[b*1280 + tid], c);      // ctx slot for L0(t+1)
      sVec[tid] = c;
      __syncthreads();
      if (tid < 80){
        float acc = 0.f;
        #pragma unroll 4
        for (int e2=0;e2<512;++e2) acc = fmaf(sVec[e2], Wfc[e2*80+tid], acc);  // cached
        out[((size_t)b*255 + t)*80 + tid] = acc + bfc[tid];
      }
    }
    gsync(bar,w,ep);
  }
}

extern "C" void kernel_launch(void* const* d_in, const int* in_sizes, int n_in,
                              void* d_out, int out_size, void* d_ws, size_t ws_size,
                              hipStream_t stream) {
  const float* tgt  = (const float*)d_in[0];
  const float* enc  = (const float*)d_in[1];
  const int*   lens = (const int*)  d_in[2];
  const float* Wih0 = (const float*)d_in[3];
  const float* Whh0 = (const float*)d_in[4];
  const float* b0   = (const float*)d_in[5];
  const float* Wih1 = (const float*)d_in[6];
  const float* Whh1 = (const float*)d_in[7];
  const float* b1   = (const float*)d_in[8];
  const float* Wih2 = (const float*)d_in[9];
  const float* Whh2 = (const float*)d_in[10];
  const float* b2   = (const float*)d_in[11];
  const float* Wq   = (const float*)d_in[12];
  const float* Wfc  = (const float*)d_in[13];
  const float* bfc  = (const float*)d_in[14];

  hipMemsetAsync(d_ws, 0, 8192, stream);   // barrier counters
  sd_kernel<<<NBLK, NTHR, 0, stream>>>(tgt, enc, lens,
                                       Wih0, Whh0, b0,
                                       Wih1, Whh1, b1,
                                       Wih2, Whh2, b2,
                                       Wq, Wfc, bfc,
                                       (float*)d_out, d_ws);
}

// Round 10
// 35688.657 us; speedup vs baseline: 1.1854x; 1.0682x over previous
//
#include <hip/hip_runtime.h>

#define NBLK 256
#define NTHR 512

typedef float f32x4 __attribute__((ext_vector_type(4)));
typedef unsigned int u32;

// ---------------- math helpers ----------------
__device__ __forceinline__ float sigm(float x){ return 1.f/(1.f+__expf(-x)); }
__device__ __forceinline__ float tanh_(float x){ return 1.f - 2.f/(__expf(2.f*x)+1.f); }

__device__ __forceinline__ float wred_sum(float v){
  #pragma unroll
  for (int off=32; off; off>>=1) v += __shfl_xor(v, off, 64);
  return v;
}

// bf16 pack/unpack
__device__ __forceinline__ u32 cvtpk(float lo, float hi){
  u32 r; asm("v_cvt_pk_bf16_f32 %0,%1,%2":"=v"(r):"v"(lo),"v"(hi)); return r;
}
__device__ __forceinline__ float bflo(u32 u){ return __uint_as_float(u<<16); }
__device__ __forceinline__ float bfhi(u32 u){ return __uint_as_float(u & 0xFFFF0000u); }

// agent-coherent (sc1) store/load
__device__ __forceinline__ void st_sys(float* p, float v){
  __hip_atomic_store(p, v, __ATOMIC_RELAXED, __HIP_MEMORY_SCOPE_AGENT);
}
__device__ __forceinline__ void st_sysu(u32* p, u32 v){
  __hip_atomic_store(p, v, __ATOMIC_RELAXED, __HIP_MEMORY_SCOPE_AGENT);
}
__device__ __forceinline__ float ald(const float* p){
  return __hip_atomic_load(p, __ATOMIC_RELAXED, __HIP_MEMORY_SCOPE_AGENT);
}
__device__ __forceinline__ u32 aldu(const u32* p){
  return __hip_atomic_load(p, __ATOMIC_RELAXED, __HIP_MEMORY_SCOPE_AGENT);
}

// two-level arrive + two-level release grid barrier, epoch-based (proven r7/r9).
__device__ __forceinline__ void gsync(unsigned* bar, int w, unsigned& ep){
  ++ep;
  __builtin_amdgcn_s_waitcnt(0);
  __syncthreads();
  if (threadIdx.x == 0){
    const int g = w >> 4;
    const unsigned epoch = ep;
    bool rootfin = false;
    unsigned o = __hip_atomic_fetch_add(bar + g*32, 1u, __ATOMIC_ACQ_REL, __HIP_MEMORY_SCOPE_AGENT);
    if (o == 15u){
      __hip_atomic_store(bar + g*32, 0u, __ATOMIC_RELAXED, __HIP_MEMORY_SCOPE_AGENT);
      unsigned o2 = __hip_atomic_fetch_add(bar + 16*32, 1u, __ATOMIC_ACQ_REL, __HIP_MEMORY_SCOPE_AGENT);
      if (o2 == 15u){
        __hip_atomic_store(bar + 16*32, 0u, __ATOMIC_RELAXED, __HIP_MEMORY_SCOPE_AGENT);
        __hip_atomic_store(bar + 17*32, epoch, __ATOMIC_RELEASE, __HIP_MEMORY_SCOPE_AGENT);
        rootfin = true;
      }
    }
    if ((w & 15) == 0){
      if (!rootfin){
        while (__hip_atomic_load(bar + 17*32, __ATOMIC_RELAXED, __HIP_MEMORY_SCOPE_AGENT) < epoch)
          __builtin_amdgcn_s_sleep(1);
      }
      __hip_atomic_store(bar + (18+g)*32, epoch, __ATOMIC_RELEASE, __HIP_MEMORY_SCOPE_AGENT);
    } else {
      while (__hip_atomic_load(bar + (18+g)*32, __ATOMIC_RELAXED, __HIP_MEMORY_SCOPE_AGENT) < epoch)
        __builtin_amdgcn_s_sleep(1);
    }
  }
  __syncthreads();
}

// ---------------- LSTM layer (bf16-state staging; fp32 compute = r9) ----
// State rows are 1024 bf16 (= 512 uints). Chunk = 8 batch rows.
// Stage layout in LDS (fp32): row stride RS (1280 L0 / 1024 L1,L2);
// L0 row = [state 0:1024)[x 1024:1104)[pad:1280) — identical to r9.

template<bool L0T>
__device__ __forceinline__ void loadch_bf(const u32* __restrict__ inu, int ch, int tid,
                                          const float* __restrict__ tgt, int t,
                                          uint4& u0, uint4& u1, f32x4& xv){
  const u32* cb = inu + ch*4096;            // 8 rows * 512 u
  asm volatile("global_load_dwordx4 %0, %1, off sc0 sc1" : "=v"(u0) : "v"(cb + (tid<<2)));
  asm volatile("global_load_dwordx4 %0, %1, off sc0 sc1" : "=v"(u1) : "v"(cb + 2048 + (tid<<2)));
  if (L0T){
    const int bloc = tid>>6, xo = (tid&63)<<2;
    if (xo < 80) xv = *(const f32x4*)(tgt + ((((ch<<3)+bloc)<<8) + t)*80 + xo);
    else         xv = (f32x4){0.f,0.f,0.f,0.f};
  }
  asm volatile("s_waitcnt vmcnt(0)" ::: "memory");
  __builtin_amdgcn_sched_barrier(0);
}

template<int RS, bool L0T>
__device__ __forceinline__ void stw_bf(float* S, int tid,
                                       const uint4& u0, const uint4& u1, const f32x4& xv){
  const int row0 = tid>>7, k = (tid&127)<<3;
  float* d0 = S + row0*RS + k;
  f32x4 a, b;
  a.x=bflo(u0.x); a.y=bfhi(u0.x); a.z=bflo(u0.y); a.w=bfhi(u0.y);
  b.x=bflo(u0.z); b.y=bfhi(u0.z); b.z=bflo(u0.w); b.w=bfhi(u0.w);
  *(f32x4*)d0 = a; *(f32x4*)(d0+4) = b;
  float* d1 = S + (4+row0)*RS + k;
  a.x=bflo(u1.x); a.y=bfhi(u1.x); a.z=bflo(u1.y); a.w=bfhi(u1.y);
  b.x=bflo(u1.z); b.y=bfhi(u1.z); b.z=bflo(u1.w); b.w=bfhi(u1.w);
  *(f32x4*)d1 = a; *(f32x4*)(d1+4) = b;
  if (L0T){
    const int bloc = tid>>6, xo = (tid&63)<<2;
    *(f32x4*)(S + bloc*RS + 1024 + xo) = xv;
  }
}

template<int NI>
__device__ __forceinline__ void cchunk(
    const float* S, int ch, int tid, int s, int r,
    const float (&wt)[NI][4], float breg,
    float* sc_c, float* sPart, float* sG4,
    u32* __restrict__ dstA, int strAu,
    u32* __restrict__ dstB, int strBu)
{
  float p[8];
  #pragma unroll
  for (int bb=0; bb<8; ++bb){
    const float* row = S + bb*(NI<<8) + (s<<2);
    float a0=0.f,a1=0.f,a2=0.f,a3=0.f;
    #pragma unroll
    for (int i=0;i<NI;++i){
      const float4 x = *(const float4*)(row + (i<<8));
      a0 = fmaf(wt[i][0], x.x, a0);
      a1 = fmaf(wt[i][1], x.y, a1);
      a2 = fmaf(wt[i][2], x.z, a2);
      a3 = fmaf(wt[i][3], x.w, a3);
    }
    p[bb] = (a0+a1)+(a2+a3);
  }
  #pragma unroll
  for (int bb=0; bb<8; ++bb)
    sPart[((((bb<<3)|r)<<6) | s)] = p[bb];
  __syncthreads();
  {
    const int seg = tid & 7, r2 = (tid>>3)&7, bb2 = tid>>6;
    const float* pp = sPart + (((bb2<<3)|r2)<<6) + (seg<<3);
    float v = ((pp[0]+pp[1])+(pp[2]+pp[3])) + ((pp[4]+pp[5])+(pp[6]+pp[7]));
    v += __shfl_xor(v,1,64);
    v += __shfl_xor(v,2,64);
    v += __shfl_xor(v,4,64);
    if (seg==0) sG4[(bb2<<3)|r2] = v + breg;
  }
  __syncthreads();
  if (tid < 16){
    const int bb = tid>>1, jl = tid&1;
    const int b = (ch<<3) + bb;
    const float gi = sigm (sG4[(bb<<3) + (jl<<2) + 0]);
    const float gf = sigm (sG4[(bb<<3) + (jl<<2) + 1]);
    const float gg = tanh_(sG4[(bb<<3) + (jl<<2) + 2]);
    const float go = sigm (sG4[(bb<<3) + (jl<<2) + 3]);
    const float cn = gf*sc_c[(ch<<4)+tid] + gi*gg;
    sc_c[(ch<<4)+tid] = cn;
    const float hn = go * tanh_(cn);
    const float hn1 = __shfl(hn, tid^1, 64);     // partner j within lanes 0..15
    if (!(tid&1)){
      const u32 hp = cvtpk(hn, hn1);             // (j=2w, j=2w+1) packed
      st_sysu(dstA + b*strAu, hp);
      st_sysu(dstB + b*strBu, hp);
    }
  }
}

template<int NI, int RS, bool L0T>
__device__ __forceinline__ void lstm_layer(
    int w, int tid, const float (&wt)[NI][4], float breg,
    const u32* __restrict__ inu, float* sc_c,
    u32* __restrict__ dstA, int strAu,
    u32* __restrict__ dstB, int strBu,
    float* S, float* sPart, float* sG4,
    const float* __restrict__ tgt, int t)
{
  const int s = tid & 63, r = tid >> 6;
  uint4 u0, u1; f32x4 xv;
  #pragma unroll 1
  for (int ch=0; ch<8; ++ch){
    loadch_bf<L0T>(inu, ch, tid, tgt, t, u0, u1, xv);
    stw_bf<RS,L0T>(S, tid, u0, u1, xv);
    __syncthreads();
    cchunk<NI>(S, ch, tid,s,r, wt,breg, sc_c,sPart,sG4, dstA,strAu, dstB,strBu);
  }
}

// ---- ws layout (after 8KB barrier area), in UINTS ----
// IN0 [2][64][512]u rows=[ctx 0:256)[h0 256:512)   @0
// IN1 [2][64][512]u rows=[h0n 0:256)[h1o 256:512)  @65536
// IN2 [2][64][512]u                                 @131072
// H2  [64][256]u                                    @196608
// fp32 region @212992 floats: QP[4][64][512], PC[4][64][512], MS[512]
// ENCBF [64][512][256]u                             @475648
#define ZERO_U   212992
#define FP_OFF   212992
#define ENC_OFF  475648
#define ENC_CNT  8388608

__global__ __launch_bounds__(NTHR, 2)
void sd_kernel(const float* __restrict__ tgt,  const float* __restrict__ enc,
               const int*   __restrict__ lens,
               const float* __restrict__ Wih0, const float* __restrict__ Whh0, const float* __restrict__ b0v,
               const float* __restrict__ Wih1, const float* __restrict__ Whh1, const float* __restrict__ b1v,
               const float* __restrict__ Wih2, const float* __restrict__ Whh2, const float* __restrict__ b2v,
               const float* __restrict__ Wq,   const float* __restrict__ Wfc,  const float* __restrict__ bfc,
               float* __restrict__ out, void* __restrict__ wsv, int ebf)
{
  unsigned* bar = (unsigned*)wsv;
  u32* wsu = (u32*)((char*)wsv + 8192);
  u32* IN0u = wsu;
  u32* IN1u = wsu + 65536;
  u32* IN2u = wsu + 131072;
  u32* H2u  = wsu + 196608;
  float* F  = (float*)(wsu + FP_OFF);
  float* QP = F;
  float* PC = F + 131072;
  float* MS = F + 262144;
  u32* encbfu = wsu + ENC_OFF;

  const int w = blockIdx.x, tid = threadIdx.x;
  const int s = tid & 63, r = tid >> 6;
  unsigned ep = 0;

  __shared__ __attribute__((aligned(16))) float sStage[10240];  // 8 x 1280 fp32
  __shared__ __attribute__((aligned(16))) float sBig[4096];
  __shared__ __attribute__((aligned(16))) float sG4[64];
  __shared__ __attribute__((aligned(16))) float sVec[512];
  __shared__ __attribute__((aligned(16))) float sSmall[16];
  __shared__ __attribute__((aligned(16))) float sc_c[384];      // 128 per layer

  // ---- prologue: weights -> registers (normal cached; stage layout unchanged) ----
  const int wrow  = ((r&3)<<9) + (w<<1) + (r>>2);
  const int r2p   = (tid>>3)&7;
  const int wrowb = ((r2p&3)<<9) + (w<<1) + (r2p>>2);

  float w0r[5][4], w1r[4][4], w2r[4][4];
  #pragma unroll
  for (int i=0;i<5;++i){
    #pragma unroll
    for (int j=0;j<4;++j){
      const int k = (i<<8) + (s<<2) + j;
      float v;
      if (k < 512)       v = Wih0[wrow*592 + 80 + k];        // ctx block
      else if (k < 1024) v = Whh0[(wrow<<9) + (k-512)];      // h0 block
      else if (k < 1104) v = Wih0[wrow*592 + (k-1024)];      // x block
      else               v = 0.f;                            // pad
      w0r[i][j] = v;
    }
  }
  #pragma unroll
  for (int i=0;i<4;++i){
    #pragma unroll
    for (int j=0;j<4;++j){
      const int k = (i<<8) + (s<<2) + j;
      w1r[i][j] = (k<512) ? Wih1[(wrow<<9)+k] : Whh1[(wrow<<9)+k-512];
      w2r[i][j] = (k<512) ? Wih2[(wrow<<9)+k] : Whh2[(wrow<<9)+k-512];
    }
  }
  const float br0 = b0v[wrowb], br1 = b1v[wrowb], br2 = b2v[wrowb];

  if (tid < 384) sc_c[tid] = 0.f;
  for (int i = w*NTHR + tid; i < ZERO_U; i += NBLK*NTHR) st_sysu(wsu + i, 0u);
  if (ebf){
    // one-time enc -> bf16 (sc1-written; read back with normal cached loads)
    for (int i = w*NTHR + tid; i < ENC_CNT; i += NBLK*NTHR)
      st_sysu(encbfu + i, cvtpk(enc[2*i], enc[2*i+1]));
  }
  gsync(bar, w, ep);

  for (int t=0; t<255; ++t){
    const int p = t & 1, np = p ^ 1;
    u32* IN0p = IN0u + p*32768;  u32* IN0n = IN0u + np*32768;
    u32* IN1p = IN1u + p*32768;  u32* IN1n = IN1u + np*32768;
    u32* IN2p = IN2u + p*32768;  u32* IN2n = IN2u + np*32768;

    lstm_layer<5,1280,true >(w,tid, w0r, br0, IN0p, sc_c,
                             IN0n+256+w, 512, IN1p+w, 512, sStage, sBig, sG4, tgt, t);
    gsync(bar,w,ep);
    lstm_layer<4,1024,false>(w,tid, w1r, br1, IN1p, sc_c+128,
                             IN1n+256+w, 512, IN2p+w, 512, sStage, sBig, sG4, tgt, t);
    gsync(bar,w,ep);
    lstm_layer<4,1024,false>(w,tid, w2r, br2, IN2p, sc_c+256,
                             IN2n+256+w, 512, H2u+w, 256, sStage, sBig, sG4, tgt, t);
    gsync(bar,w,ep);

    // ---- q partials: WG (b = w&63, kq = w>>6) over k-quarter ----
    {
      const int b = w & 63, kq = w >> 6;
      if (tid < 64){
        const u32 u = aldu(H2u + b*256 + kq*64 + tid);
        sVec[2*tid]   = bflo(u);
        sVec[2*tid+1] = bfhi(u);
      }
      __syncthreads();
      const float* wqp = Wq + ((size_t)(kq<<7)<<9) + tid;     // normal cached (L2-hot)
      float acc = 0.f;
      #pragma unroll 4
      for (int k=0;k<128;++k) acc = fmaf(sVec[k], wqp[(size_t)k<<9], acc);
      st_sys(&QP[(((kq<<6)+b)<<9) + tid], acc);
    }
    gsync(bar,w,ep);

    // ---- attention A: WG (b, sq): online-softmax over 128 enc rows ----
    {
      const int b = w & 63, sq = w >> 6;
      const int len  = lens[b];
      const int lane = tid & 63, wv = tid >> 6;
      sVec[tid] = ald(&QP[(b<<9)+tid]) + ald(&QP[((64+b)<<9)+tid])
                + ald(&QP[((128+b)<<9)+tid]) + ald(&QP[((192+b)<<9)+tid]);
      __syncthreads();
      const float4 qA = *(const float4*)(sVec + (lane<<3));
      const float4 qB = *(const float4*)(sVec + (lane<<3) + 4);
      float mr = -3.0e38f, lr = 0.f;
      float c0=0,c1=0,c2=0,c3=0,c4=0,c5=0,c6=0,c7=0;
      const float scale = 0.04419417382415922f;   // 1/sqrt(512)
      if (ebf){
        const u32* ebase = encbfu + (((size_t)b)<<17) + (lane<<2);
        #pragma unroll 1
        for (int rr=0; rr<16; ++rr){
          const int srow = (sq<<7) + (wv<<4) + rr;
          if (srow >= len) break;
          const uint4 eu = *(const uint4*)(ebase + ((size_t)srow<<8));  // normal cached
          const float e0=bflo(eu.x), e1=bfhi(eu.x), e2=bflo(eu.y), e3=bfhi(eu.y);
          const float e4=bflo(eu.z), e5=bfhi(eu.z), e6=bflo(eu.w), e7=bfhi(eu.w);
          float d0 = qA.x*e0, d1 = qA.y*e1, d2 = qA.z*e2, d3 = qA.w*e3;
          d0 = fmaf(qB.x, e4, d0); d1 = fmaf(qB.y, e5, d1);
          d2 = fmaf(qB.z, e6, d2); d3 = fmaf(qB.w, e7, d3);
          float d = wred_sum((d0+d1)+(d2+d3));
          const float sc = d*scale;
          const float mn = fmaxf(mr, sc);
          const float sf = __expf(mr - mn);
          const float pe = __expf(sc - mn);
          lr = fmaf(lr, sf, pe);
          c0 = fmaf(c0, sf, pe*e0); c1 = fmaf(c1, sf, pe*e1);
          c2 = fmaf(c2, sf, pe*e2); c3 = fmaf(c3, sf, pe*e3);
          c4 = fmaf(c4, sf, pe*e4); c5 = fmaf(c5, sf, pe*e5);
          c6 = fmaf(c6, sf, pe*e6); c7 = fmaf(c7, sf, pe*e7);
          mr = mn;
        }
      } else {
        #pragma unroll 1
        for (int rr=0; rr<16; ++rr){
          const int srow = (sq<<7) + (wv<<4) + rr;
          if (srow >= len) break;
          const float* ep2 = enc + (((size_t)(b<<9)+srow)<<9) + (lane<<3);
          const float4 e0v = *(const float4*)(ep2);
          const float4 e1v = *(const float4*)(ep2+4);
          float d0 = qA.x*e0v.x, d1 = qA.y*e0v.y, d2 = qA.z*e0v.z, d3 = qA.w*e0v.w;
          d0 = fmaf(qB.x, e1v.x, d0); d1 = fmaf(qB.y, e1v.y, d1);
          d2 = fmaf(qB.z, e1v.z, d2); d3 = fmaf(qB.w, e1v.w, d3);
          float d = wred_sum((d0+d1)+(d2+d3));
          const float sc = d*scale;
          const float mn = fmaxf(mr, sc);
          const float sf = __expf(mr - mn);
          const float pe = __expf(sc - mn);
          lr = fmaf(lr, sf, pe);
          c0 = fmaf(c0, sf, pe*e0v.x); c1 = fmaf(c1, sf, pe*e0v.y);
          c2 = fmaf(c2, sf, pe*e0v.z); c3 = fmaf(c3, sf, pe*e0v.w);
          c4 = fmaf(c4, sf, pe*e1v.x); c5 = fmaf(c5, sf, pe*e1v.y);
          c6 = fmaf(c6, sf, pe*e1v.z); c7 = fmaf(c7, sf, pe*e1v.w);
          mr = mn;
        }
      }
      if (lane==0){ sSmall[wv] = mr; sSmall[8+wv] = lr; }
      {
        float4 v0 = {c0,c1,c2,c3}, v1 = {c4,c5,c6,c7};
        *(float4*)(sBig + (wv<<9) + (lane<<3))     = v0;
        *(float4*)(sBig + (wv<<9) + (lane<<3) + 4) = v1;
      }
      __syncthreads();
      float M = sSmall[0];
      #pragma unroll
      for (int i=1;i<8;++i) M = fmaxf(M, sSmall[i]);
      float L = 0.f, acc = 0.f;
      #pragma unroll
      for (int i=0;i<8;++i){
        const float A = __expf(sSmall[i]-M);
        L   = fmaf(A, sSmall[8+i], L);
        acc = fmaf(A, sBig[(i<<9)+tid], acc);
      }
      st_sys(&PC[(((sq<<6)+b)<<9)+tid], acc);
      if (tid==0){
        st_sys(&MS[(((sq<<6)+b)<<1)],   M);
        st_sys(&MS[(((sq<<6)+b)<<1)+1], L);
      }
    }
    gsync(bar,w,ep);

    // ---- attention B: combine + FC + out (WGs 0..63 only) ----
    if (w < 64){
      const int b = w;
      const float m0 = ald(&MS[(b)<<1]),      S0 = ald(&MS[((b)<<1)+1]);
      const float m1 = ald(&MS[(64+b)<<1]),   S1 = ald(&MS[((64+b)<<1)+1]);
      const float m2 = ald(&MS[(128+b)<<1]),  S2 = ald(&MS[((128+b)<<1)+1]);
      const float m3 = ald(&MS[(192+b)<<1]),  S3 = ald(&MS[((192+b)<<1)+1]);
      const float M  = fmaxf(fmaxf(m0,m1), fmaxf(m2,m3));
      const float a0=__expf(m0-M), a1=__expf(m1-M), a2=__expf(m2-M), a3=__expf(m3-M);
      const float inv = 1.f/(a0*S0 + a1*S1 + a2*S2 + a3*S3);
      const float c = (a0*ald(&PC[(b<<9)+tid])       + a1*ald(&PC[((64+b)<<9)+tid])
                     + a2*ald(&PC[((128+b)<<9)+tid]) + a3*ald(&PC[((192+b)<<9)+tid])) * inv;
      // recurrent ctx in bf16 (paired store); pred uses fp32 ctx below
      const float c1 = __shfl(c, tid^1, 64);
      if (!(tid&1)) st_sysu(IN0n + b*512 + (tid>>1), cvtpk(c, c1));
      sVec[tid] = c;
      __syncthreads();
      if (tid < 80){
        float acc = 0.f;
        #pragma unroll 4
        for (int e2=0;e2<512;++e2) acc = fmaf(sVec[e2], Wfc[e2*80+tid], acc);  // cached
        out[((size_t)b*255 + t)*80 + tid] = acc + bfc[tid];
      }
    }
    gsync(bar,w,ep);
  }
}

extern "C" void kernel_launch(void* const* d_in, const int* in_sizes, int n_in,
                              void* d_out, int out_size, void* d_ws, size_t ws_size,
                              hipStream_t stream) {
  const float* tgt  = (const float*)d_in[0];
  const float* enc  = (const float*)d_in[1];
  const int*   lens = (const int*)  d_in[2];
  const float* Wih0 = (const float*)d_in[3];
  const float* Whh0 = (const float*)d_in[4];
  const float* b0   = (const float*)d_in[5];
  const float* Wih1 = (const float*)d_in[6];
  const float* Whh1 = (const float*)d_in[7];
  const float* b1   = (const float*)d_in[8];
  const float* Wih2 = (const float*)d_in[9];
  const float* Whh2 = (const float*)d_in[10];
  const float* b2   = (const float*)d_in[11];
  const float* Wq   = (const float*)d_in[12];
  const float* Wfc  = (const float*)d_in[13];
  const float* bfc  = (const float*)d_in[14];

  const size_t need = 8192ull + ((size_t)ENC_OFF + (size_t)ENC_CNT)*4ull;
  const int ebf = (ws_size >= need) ? 1 : 0;

  hipMemsetAsync(d_ws, 0, 8192, stream);   // barrier counters
  sd_kernel<<<NBLK, NTHR, 0, stream>>>(tgt, enc, lens,
                                       Wih0, Whh0, b0,
                                       Wih1, Whh1, b1,
                                       Wih2, Whh2, b2,
                                       Wq, Wfc, bfc,
                                       (float*)d_out, d_ws, ebf);
}